// Round 1
// baseline (638.191 us; speedup 1.0000x reference)
//
#include <hip/hip_runtime.h>
#include <cstdint>

typedef __attribute__((ext_vector_type(8))) short short8;
typedef __attribute__((ext_vector_type(4))) float f32x4;

#define BPB 16          // batches per block
#define ROWS 192        // BPB * 12 rows of H per block
#define HP  136         // H LDS pitch in bf16 elems (272 B = 17*16, 16B-aligned rows)

__device__ inline unsigned short f2bf(float f) {
    union { float f; unsigned int u; } v; v.f = f;
    unsigned int r = v.u + 0x7FFFu + ((v.u >> 16) & 1u);   // round-to-nearest-even
    return (unsigned short)(r >> 16);
}
__device__ inline float bf2f(unsigned short h) {
    union { unsigned int u; float f; } v; v.u = ((unsigned int)h) << 16;
    return v.f;
}

// Prep: Wt[d][k] = bf16(W[k][d]);  W is [256][128] row-major.  64 KB output in d_ws.
__global__ void wprep_kernel(const float* __restrict__ W, unsigned short* __restrict__ wt) {
    int idx = blockIdx.x * 256 + threadIdx.x;     // 0..32767
    int k = idx >> 7, d = idx & 127;
    wt[d * 256 + k] = f2bf(W[idx]);
}

__global__ __launch_bounds__(256, 2)
void gat_kernel(const float* __restrict__ x, const float* __restrict__ adj,
                const unsigned short* __restrict__ wt, const float* __restrict__ a,
                float* __restrict__ out) {
    __shared__ unsigned short Hlds[ROWS * HP];   // 52224 B, bf16 H
    __shared__ float alphaLds[ROWS * 12];        // 9216 B
    __shared__ float sI[ROWS], sJ[ROWS];
    __shared__ float adjLds[144];
    __shared__ float aLo[128], aHi[128];

    const int tid = threadIdx.x;
    const int wave = tid >> 6, lane = tid & 63;
    const int lane15 = lane & 15, quad = lane >> 4;

    // ---- phase 0: preload small tensors (covered by the post-H barrier) ----
    if (tid < 144) adjLds[tid] = adj[tid];
    if (tid < 128) { aLo[tid] = a[tid]; aHi[tid] = a[128 + tid]; }

    // ---- phase 1: H = x @ W via bf16 MFMA; wave handles 48 rows x 128 d ----
    // A operand = Wt tile (m = d-index), B operand = x rows (n = row-index).
    // A-frag: lane holds A[m=lane15][k=quad*8+j]; B-frag: B[k=quad*8+j][n=lane15].
    // D: lane reg r -> H[row = lane15][d = quad*4 + r].
    f32x4 acc[3][8];
#pragma unroll
    for (int rt = 0; rt < 3; ++rt)
#pragma unroll
        for (int dt = 0; dt < 8; ++dt)
            acc[rt][dt] = f32x4{0.f, 0.f, 0.f, 0.f};

    const long blockRow0 = (long)blockIdx.x * ROWS;
    const float* xw = x + (blockRow0 + (long)(wave * 48 + lane15)) * 256;

    for (int kt = 0; kt < 8; ++kt) {
        const int k0 = kt * 32 + quad * 8;
        short8 xf[3];
#pragma unroll
        for (int rt = 0; rt < 3; ++rt) {
            const float* p = xw + rt * 16 * 256 + k0;
            f32x4 lo = *(const f32x4*)p;
            f32x4 hi = *(const f32x4*)(p + 4);
            short8 s;
            s[0] = (short)f2bf(lo[0]); s[1] = (short)f2bf(lo[1]);
            s[2] = (short)f2bf(lo[2]); s[3] = (short)f2bf(lo[3]);
            s[4] = (short)f2bf(hi[0]); s[5] = (short)f2bf(hi[1]);
            s[6] = (short)f2bf(hi[2]); s[7] = (short)f2bf(hi[3]);
            xf[rt] = s;
        }
        short8 wf[8];
#pragma unroll
        for (int dt = 0; dt < 8; ++dt)
            wf[dt] = *(const short8*)(wt + (dt * 16 + lane15) * 256 + k0);
#pragma unroll
        for (int rt = 0; rt < 3; ++rt)
#pragma unroll
            for (int dt = 0; dt < 8; ++dt)
                acc[rt][dt] = __builtin_amdgcn_mfma_f32_16x16x32_bf16(
                    wf[dt], xf[rt], acc[rt][dt], 0, 0, 0);
    }

    // H -> LDS (bf16).  4 consecutive d per lane-reg quartet -> one b64 write.
#pragma unroll
    for (int rt = 0; rt < 3; ++rt) {
        int row = wave * 48 + rt * 16 + lane15;
#pragma unroll
        for (int dt = 0; dt < 8; ++dt) {
            int d0 = dt * 16 + quad * 4;
            f32x4 v = acc[rt][dt];
            union { unsigned short s[4]; uint2 u; } pk;
            pk.s[0] = f2bf(v[0]); pk.s[1] = f2bf(v[1]);
            pk.s[2] = f2bf(v[2]); pk.s[3] = f2bf(v[3]);
            *(uint2*)&Hlds[row * HP + d0] = pk.u;
        }
    }
    __syncthreads();

    // ---- phase 2a: s_i = H.a_hi, s_j = H.a_lo (one thread per row) ----
    if (tid < ROWS) {
        float si = 0.f, sj = 0.f;
#pragma unroll
        for (int dg = 0; dg < 16; ++dg) {
            short8 h8 = *(const short8*)&Hlds[tid * HP + dg * 8];
#pragma unroll
            for (int t = 0; t < 8; ++t) {
                float hv = bf2f((unsigned short)h8[t]);
                si += hv * aHi[dg * 8 + t];
                sj += hv * aLo[dg * 8 + t];
            }
        }
        sI[tid] = si; sJ[tid] = sj;
    }
    __syncthreads();

    // ---- phase 2b: masked softmax -> alpha (one thread per (batch, i)) ----
    if (tid < ROWS) {
        int b = tid / 12, i = tid - b * 12;
        int base = b * 12;
        float si = sI[base + i];
        float ev[12];
        float m = -3.0e38f;
#pragma unroll
        for (int j = 0; j < 12; ++j) {
            float z = si + sJ[base + j];
            z = z > 0.f ? z : 0.2f * z;                       // leaky_relu(0.2)
            z = (adjLds[i * 12 + j] == 1.0f) ? z : -1.0e30f;  // mask
            ev[j] = z;
            m = fmaxf(m, z);
        }
        float sum = 0.f;
#pragma unroll
        for (int j = 0; j < 12; ++j) {
            float t = __expf(ev[j] - m);
            ev[j] = t; sum += t;
        }
        float inv = 1.0f / sum;
#pragma unroll
        for (int j = 0; j < 12; ++j)
            alphaLds[tid * 12 + j] = ev[j] * inv;
    }
    __syncthreads();

    // ---- phase 3: h' = alpha @ H, ELU, store.  Wave: 4 batches; lanes = 4 rows x 16 dgroups ----
    const long outBatch0 = (long)blockIdx.x * BPB;
    for (int bl = 0; bl < 4; ++bl) {
        int b = wave * 4 + bl;
        int rowBase = b * 12;
#pragma unroll
        for (int it = 0; it < 3; ++it) {
            int i = it * 4 + quad;
            float al[12];
#pragma unroll
            for (int j = 0; j < 12; ++j) al[j] = alphaLds[(rowBase + i) * 12 + j];
            float o[8] = {0.f,0.f,0.f,0.f,0.f,0.f,0.f,0.f};
#pragma unroll
            for (int j = 0; j < 12; ++j) {
                short8 h8 = *(const short8*)&Hlds[(rowBase + j) * HP + lane15 * 8];
                float aj = al[j];
#pragma unroll
                for (int t = 0; t < 8; ++t)
                    o[t] += aj * bf2f((unsigned short)h8[t]);
            }
#pragma unroll
            for (int t = 0; t < 8; ++t)
                o[t] = o[t] > 0.f ? o[t] : (__expf(o[t]) - 1.0f);  // ELU
            float* op = out + ((outBatch0 + b) * 12 + i) * 128 + lane15 * 8;
            f32x4 v0 = {o[0], o[1], o[2], o[3]};
            f32x4 v1 = {o[4], o[5], o[6], o[7]};
            *(f32x4*)op = v0;
            *(f32x4*)(op + 4) = v1;
        }
    }
}

extern "C" void kernel_launch(void* const* d_in, const int* in_sizes, int n_in,
                              void* d_out, int out_size, void* d_ws, size_t ws_size,
                              hipStream_t stream) {
    const float* x   = (const float*)d_in[0];   // [32768,12,256]
    const float* adj = (const float*)d_in[1];   // [12,12]
    const float* W   = (const float*)d_in[2];   // [256,128]
    const float* a   = (const float*)d_in[3];   // [256,1]
    float* out = (float*)d_out;                 // [32768,12,128]
    unsigned short* wt = (unsigned short*)d_ws; // 64 KB bf16 W^T

    hipLaunchKernelGGL(wprep_kernel, dim3(128), dim3(256), 0, stream, W, wt);
    hipLaunchKernelGGL(gat_kernel, dim3(2048), dim3(256), 0, stream, x, adj, wt, a, out);
}